// Round 2
// baseline (86.709 us; speedup 1.0000x reference)
//
#include <hip/hip_runtime.h>
#include <math.h>

#define BB    8
#define NN    4096
#define DIRS  2
#define TPB   256
#define Q     16                // queries per thread (register-resident)
#define RSIZE 128               // refs per block (LDS-staged)
#define RC    (NN / RSIZE)      // 32 ref chunks
#define CDN   (DIRS * BB * NN)  // 65536 query slots (both directions)
#define RBLK  128               // reduce blocks

// v_min3_f32: exact 3-input min for finite floats (and +inf accumulator).
// clang will NOT pattern-match fminf chains to min3 without nnan fast-math,
// so force it. "+v" read-modify-write keeps it a single register.
__device__ __forceinline__ void min3_acc(float& m, float a, float b) {
    asm volatile("v_min3_f32 %0, %1, %2, %0" : "+v"(m) : "v"(a), "v"(b));
}

// --- Kernel 1: brute-force chamfer partial mins --------------------------
// d2 = |q - r|^2 = q^2 + (r^2 - 2 q.r). Track min over refs of
// (r^2 - 2 q.r) with (-2rx, -2ry, r^2) staged in LDS.
// Q=16 queries/thread so each ds_read_b128 broadcast feeds 40 VALU ops:
// LDS pipe at ~50-60%, VALU at 2.5 ops/pair (2 fma + 0.5 min3).
__global__ __launch_bounds__(TPB) void chamfer_kernel(
    const float* __restrict__ y_true, const float* __restrict__ y_pred,
    float* __restrict__ part)
{
    __shared__ float4 refs[RSIZE];
    const int rc  = blockIdx.x;     // ref chunk
    const int dir = blockIdx.y;     // 0: true->pred, 1: pred->true
    const int b   = blockIdx.z;

    const float2* qbase = (const float2*)(dir == 0 ? y_true : y_pred) + (size_t)b * NN;
    const float2* rbase = (const float2*)(dir == 0 ? y_pred : y_true) + (size_t)b * NN;

    const int t = threadIdx.x;
    if (t < RSIZE) {
        float2 r = rbase[rc * RSIZE + t];
        refs[t] = make_float4(-2.f * r.x, -2.f * r.y,
                              r.x * r.x + r.y * r.y, 0.f);
    }
    __syncthreads();

    float qx[Q], qy[Q], m[Q];
    #pragma unroll
    for (int j = 0; j < Q; ++j) {
        float2 qv = qbase[j * TPB + t];          // Q*TPB == NN, coalesced
        qx[j] = qv.x; qy[j] = qv.y; m[j] = INFINITY;
    }

    #pragma unroll 4
    for (int k = 0; k < RSIZE; k += 2) {
        float4 r0 = refs[k + 0];
        float4 r1 = refs[k + 1];
        #pragma unroll
        for (int j = 0; j < Q; ++j) {
            float d0 = fmaf(qy[j], r0.y, fmaf(qx[j], r0.x, r0.z));
            float d1 = fmaf(qy[j], r1.y, fmaf(qx[j], r1.x, r1.z));
            min3_acc(m[j], d0, d1);              // 1 inst for 2 refs
        }
    }

    #pragma unroll
    for (int j = 0; j < Q; ++j) {
        int q = j * TPB + t;
        float v = fmaxf(m[j] + (qx[j] * qx[j] + qy[j] * qy[j]), 0.f);
        // layout: part[rc][dir][b][q]  ==  rc*CDN + (dir*BB + b)*NN + q
        part[(size_t)rc * CDN + ((size_t)dir * BB + b) * NN + q] = v;
    }
}

// --- Kernel 2: combine partials + EMD, block partial sums ----------------
__global__ __launch_bounds__(TPB) void reduce_kernel(
    const float* __restrict__ y_true, const float* __restrict__ y_pred,
    const float* __restrict__ part, float* __restrict__ blocksum)
{
    const float cd_scale  = 1.0f / (float)BB;
    const float emd_scale = 1.0f / (2.0f * (float)BB * (float)NN);

    float acc = 0.f;
    const int gsz = gridDim.x * blockDim.x;
    const int gid = blockIdx.x * blockDim.x + threadIdx.x;

    for (int i = gid; i < CDN; i += gsz) {
        float mv = INFINITY;
        #pragma unroll
        for (int rc = 0; rc < RC; rc += 2) {
            float a = part[(size_t)(rc + 0) * CDN + i];
            float c = part[(size_t)(rc + 1) * CDN + i];
            min3_acc(mv, a, c);
        }
        acc += mv * cd_scale;
    }

    const float2* tp = (const float2*)y_true;
    const float2* pp = (const float2*)y_pred;
    for (int i = gid; i < BB * NN; i += gsz) {
        float2 tv = tp[i], pv = pp[i];
        float c1 = tv.x - pv.x;                      // cumsum[0] diff
        float c2 = (tv.x + tv.y) - (pv.x + pv.y);    // cumsum[1] diff
        acc = fmaf(c1 * emd_scale, c1, acc);
        acc = fmaf(c2 * emd_scale, c2, acc);
    }

    #pragma unroll
    for (int off = 32; off > 0; off >>= 1)
        acc += __shfl_down(acc, off, 64);

    __shared__ float wsum[TPB / 64];
    const int lane = threadIdx.x & 63, wid = threadIdx.x >> 6;
    if (lane == 0) wsum[wid] = acc;
    __syncthreads();
    if (threadIdx.x == 0) {
        float s = 0.f;
        #pragma unroll
        for (int w = 0; w < TPB / 64; ++w) s += wsum[w];
        blocksum[blockIdx.x] = s;
    }
}

// --- Kernel 3: final sum over RBLK block partials ------------------------
__global__ void final_kernel(const float* __restrict__ blocksum,
                             float* __restrict__ out)
{
    float v = blocksum[threadIdx.x] + blocksum[threadIdx.x + 64];
    #pragma unroll
    for (int off = 32; off > 0; off >>= 1)
        v += __shfl_down(v, off, 64);
    if (threadIdx.x == 0) out[0] = v;
}

extern "C" void kernel_launch(void* const* d_in, const int* in_sizes, int n_in,
                              void* d_out, int out_size, void* d_ws, size_t ws_size,
                              hipStream_t stream) {
    const float* y_true = (const float*)d_in[0];
    const float* y_pred = (const float*)d_in[1];
    float* out = (float*)d_out;

    float* part     = (float*)d_ws;                 // RC*CDN floats = 8 MiB
    float* blocksum = part + (size_t)RC * CDN;      // RBLK floats

    chamfer_kernel<<<dim3(RC, DIRS, BB), TPB, 0, stream>>>(y_true, y_pred, part);
    reduce_kernel<<<RBLK, TPB, 0, stream>>>(y_true, y_pred, part, blocksum);
    final_kernel<<<1, 64, 0, stream>>>(blocksum, out);
}

// Round 3
// 85.141 us; speedup vs baseline: 1.0184x; 1.0184x over previous
//
#include <hip/hip_runtime.h>
#include <math.h>

#define BB    8
#define NN    4096
#define DIRS  2
#define TPB   256
#define Q     16                // queries per thread (register-resident)
#define RSIZE 256               // refs per block (LDS-staged)
#define RC    (NN / RSIZE)      // 16 ref chunks
#define CDN   (DIRS * BB * NN)  // 65536 query slots (both directions)
#define RBLK  128               // reduce blocks

// --- Kernel 1: brute-force chamfer partial mins --------------------------
// d2 = |q - r|^2 = q^2 + (r^2 - 2 q.r). Track min over refs of
// (r^2 - 2 q.r) with (-2rx, -2ry, r^2) staged in LDS.
// Q=16 queries/thread so each ds_read_b128 broadcast feeds 48 VALU ops:
// VALU is the bound at 3 ops/pair; 16 independent chains give the ILP
// needed to saturate issue even at 1 wave/SIMD (grid = 256 blocks = 1/CU).
__global__ __launch_bounds__(TPB) void chamfer_kernel(
    const float* __restrict__ y_true, const float* __restrict__ y_pred,
    float* __restrict__ part)
{
    __shared__ float4 refs[RSIZE];
    const int rc  = blockIdx.x;     // ref chunk
    const int dir = blockIdx.y;     // 0: true->pred, 1: pred->true
    const int b   = blockIdx.z;

    const float2* qbase = (const float2*)(dir == 0 ? y_true : y_pred) + (size_t)b * NN;
    const float2* rbase = (const float2*)(dir == 0 ? y_pred : y_true) + (size_t)b * NN;

    const int t = threadIdx.x;
    if (t < RSIZE) {
        float2 r = rbase[rc * RSIZE + t];
        refs[t] = make_float4(-2.f * r.x, -2.f * r.y,
                              r.x * r.x + r.y * r.y, 0.f);
    }
    __syncthreads();

    float qx[Q], qy[Q], m[Q];
    #pragma unroll
    for (int j = 0; j < Q; ++j) {
        float2 qv = qbase[j * TPB + t];          // Q*TPB == NN, coalesced
        qx[j] = qv.x; qy[j] = qv.y; m[j] = INFINITY;
    }

    #pragma unroll 4
    for (int k = 0; k < RSIZE; ++k) {
        float4 r = refs[k];
        #pragma unroll
        for (int j = 0; j < Q; ++j) {
            float d = fmaf(qy[j], r.y, fmaf(qx[j], r.x, r.z));
            m[j] = fminf(m[j], d);
        }
    }

    #pragma unroll
    for (int j = 0; j < Q; ++j) {
        int q = j * TPB + t;
        float v = fmaxf(m[j] + (qx[j] * qx[j] + qy[j] * qy[j]), 0.f);
        // layout: part[rc][dir][b][q]  ==  rc*CDN + (dir*BB + b)*NN + q
        part[(size_t)rc * CDN + ((size_t)dir * BB + b) * NN + q] = v;
    }
}

// --- Kernel 2: combine partials + EMD, block partial sums ----------------
__global__ __launch_bounds__(TPB) void reduce_kernel(
    const float* __restrict__ y_true, const float* __restrict__ y_pred,
    const float* __restrict__ part, float* __restrict__ blocksum)
{
    const float cd_scale  = 1.0f / (float)BB;
    const float emd_scale = 1.0f / (2.0f * (float)BB * (float)NN);

    float acc = 0.f;
    const int gsz = gridDim.x * blockDim.x;
    const int gid = blockIdx.x * blockDim.x + threadIdx.x;

    for (int i = gid; i < CDN; i += gsz) {
        float mv = part[i];
        #pragma unroll
        for (int rc = 1; rc < RC; ++rc)
            mv = fminf(mv, part[(size_t)rc * CDN + i]);
        acc += mv * cd_scale;
    }

    const float2* tp = (const float2*)y_true;
    const float2* pp = (const float2*)y_pred;
    for (int i = gid; i < BB * NN; i += gsz) {
        float2 tv = tp[i], pv = pp[i];
        float c1 = tv.x - pv.x;                      // cumsum[0] diff
        float c2 = (tv.x + tv.y) - (pv.x + pv.y);    // cumsum[1] diff
        acc = fmaf(c1 * emd_scale, c1, acc);
        acc = fmaf(c2 * emd_scale, c2, acc);
    }

    #pragma unroll
    for (int off = 32; off > 0; off >>= 1)
        acc += __shfl_down(acc, off, 64);

    __shared__ float wsum[TPB / 64];
    const int lane = threadIdx.x & 63, wid = threadIdx.x >> 6;
    if (lane == 0) wsum[wid] = acc;
    __syncthreads();
    if (threadIdx.x == 0) {
        float s = 0.f;
        #pragma unroll
        for (int w = 0; w < TPB / 64; ++w) s += wsum[w];
        blocksum[blockIdx.x] = s;
    }
}

// --- Kernel 3: final sum over RBLK block partials ------------------------
__global__ void final_kernel(const float* __restrict__ blocksum,
                             float* __restrict__ out)
{
    float v = blocksum[threadIdx.x] + blocksum[threadIdx.x + 64];
    #pragma unroll
    for (int off = 32; off > 0; off >>= 1)
        v += __shfl_down(v, off, 64);
    if (threadIdx.x == 0) out[0] = v;
}

extern "C" void kernel_launch(void* const* d_in, const int* in_sizes, int n_in,
                              void* d_out, int out_size, void* d_ws, size_t ws_size,
                              hipStream_t stream) {
    const float* y_true = (const float*)d_in[0];
    const float* y_pred = (const float*)d_in[1];
    float* out = (float*)d_out;

    float* part     = (float*)d_ws;                 // RC*CDN floats = 4 MiB
    float* blocksum = part + (size_t)RC * CDN;      // RBLK floats

    chamfer_kernel<<<dim3(RC, DIRS, BB), TPB, 0, stream>>>(y_true, y_pred, part);
    reduce_kernel<<<RBLK, TPB, 0, stream>>>(y_true, y_pred, part, blocksum);
    final_kernel<<<1, 64, 0, stream>>>(blocksum, out);
}

// Round 4
// 77.048 us; speedup vs baseline: 1.1254x; 1.1050x over previous
//
#include <hip/hip_runtime.h>
#include <math.h>

#define BB    8
#define NN    4096
#define DIRS  2
#define TPB   256
#define Q     16                // queries per thread (register-resident)
#define RSIZE 128               // refs per block (LDS-staged)
#define RP    (RSIZE / 2)       // ref PAIRS per block
#define RC    (NN / RSIZE)      // 32 ref chunks
#define CDN   (DIRS * BB * NN)  // 65536 query slots (both directions)
#define RBLK  128               // reduce blocks

typedef float v2f __attribute__((ext_vector_type(2)));

// --- Kernel 1: brute-force chamfer partial mins --------------------------
// d2 = |q - r|^2 = q^2 + (r^2 - 2 q.r). Track min over refs of
// (r^2 - 2 q.r), refs packed PAIRWISE so the two fmas per ref-pair become
// v_pk_fma_f32 (gfx90a+ dual-FP32): 2 pk_fma + 2 v_min per 2 refs
// = 2.0 VALU ops/pair vs 3.0 scalar. min over even/odd partitions then
// combined at the end — bitwise-identical for finite inputs.
// Grid stays 512 blocks (2 waves/SIMD — 1 wave/SIMD exposed LDS latency, R3).
__global__ __launch_bounds__(TPB) void chamfer_kernel(
    const float* __restrict__ y_true, const float* __restrict__ y_pred,
    float* __restrict__ part)
{
    __shared__ float4 rxy[RP];   // (rx0, rx1, ry0, ry1) per pair
    __shared__ float2 rzz[RP];   // (rz0, rz1) per pair
    const int rc  = blockIdx.x;     // ref chunk
    const int dir = blockIdx.y;     // 0: true->pred, 1: pred->true
    const int b   = blockIdx.z;

    const float2* qbase = (const float2*)(dir == 0 ? y_true : y_pred) + (size_t)b * NN;
    const float2* rbase = (const float2*)(dir == 0 ? y_pred : y_true) + (size_t)b * NN;

    const int t = threadIdx.x;
    if (t < RP) {
        // two consecutive refs = one float4 global load
        float4 rr = ((const float4*)(rbase + rc * RSIZE))[t];
        rxy[t] = make_float4(-2.f * rr.x, -2.f * rr.z,
                             -2.f * rr.y, -2.f * rr.w);
        rzz[t] = make_float2(rr.x * rr.x + rr.y * rr.y,
                             rr.z * rr.z + rr.w * rr.w);
    }
    __syncthreads();

    float qx[Q], qy[Q];
    v2f m2[Q];
    #pragma unroll
    for (int j = 0; j < Q; ++j) {
        float2 qv = qbase[j * TPB + t];          // Q*TPB == NN, coalesced
        qx[j] = qv.x; qy[j] = qv.y;
        m2[j] = (v2f){INFINITY, INFINITY};
    }

    #pragma unroll 4
    for (int p = 0; p < RP; ++p) {
        float4 a = rxy[p];                       // ds_read_b128 (broadcast)
        float2 c = rzz[p];                       // ds_read_b64  (broadcast)
        v2f rx2 = (v2f){a.x, a.y};
        v2f ry2 = (v2f){a.z, a.w};
        v2f rz2 = (v2f){c.x, c.y};
        #pragma unroll
        for (int j = 0; j < Q; ++j) {
            v2f qx2 = (v2f){qx[j], qx[j]};
            v2f qy2 = (v2f){qy[j], qy[j]};
            v2f d = __builtin_elementwise_fma(qx2, rx2, rz2);   // v_pk_fma_f32
            d     = __builtin_elementwise_fma(qy2, ry2, d);     // v_pk_fma_f32
            m2[j] = __builtin_elementwise_min(m2[j], d);        // 2x v_min_f32
        }
    }

    #pragma unroll
    for (int j = 0; j < Q; ++j) {
        int q = j * TPB + t;
        float mm = fminf(m2[j].x, m2[j].y);
        float v = fmaxf(mm + (qx[j] * qx[j] + qy[j] * qy[j]), 0.f);
        // layout: part[rc][dir][b][q]  ==  rc*CDN + (dir*BB + b)*NN + q
        part[(size_t)rc * CDN + ((size_t)dir * BB + b) * NN + q] = v;
    }
}

// --- Kernel 2: combine partials + EMD, block partial sums ----------------
__global__ __launch_bounds__(TPB) void reduce_kernel(
    const float* __restrict__ y_true, const float* __restrict__ y_pred,
    const float* __restrict__ part, float* __restrict__ blocksum)
{
    const float cd_scale  = 1.0f / (float)BB;
    const float emd_scale = 1.0f / (2.0f * (float)BB * (float)NN);

    float acc = 0.f;
    const int gsz = gridDim.x * blockDim.x;
    const int gid = blockIdx.x * blockDim.x + threadIdx.x;

    for (int i = gid; i < CDN; i += gsz) {
        float mv = part[i];
        #pragma unroll
        for (int rc = 1; rc < RC; ++rc)
            mv = fminf(mv, part[(size_t)rc * CDN + i]);
        acc += mv * cd_scale;
    }

    const float2* tp = (const float2*)y_true;
    const float2* pp = (const float2*)y_pred;
    for (int i = gid; i < BB * NN; i += gsz) {
        float2 tv = tp[i], pv = pp[i];
        float c1 = tv.x - pv.x;                      // cumsum[0] diff
        float c2 = (tv.x + tv.y) - (pv.x + pv.y);    // cumsum[1] diff
        acc = fmaf(c1 * emd_scale, c1, acc);
        acc = fmaf(c2 * emd_scale, c2, acc);
    }

    #pragma unroll
    for (int off = 32; off > 0; off >>= 1)
        acc += __shfl_down(acc, off, 64);

    __shared__ float wsum[TPB / 64];
    const int lane = threadIdx.x & 63, wid = threadIdx.x >> 6;
    if (lane == 0) wsum[wid] = acc;
    __syncthreads();
    if (threadIdx.x == 0) {
        float s = 0.f;
        #pragma unroll
        for (int w = 0; w < TPB / 64; ++w) s += wsum[w];
        blocksum[blockIdx.x] = s;
    }
}

// --- Kernel 3: final sum over RBLK block partials ------------------------
__global__ void final_kernel(const float* __restrict__ blocksum,
                             float* __restrict__ out)
{
    float v = blocksum[threadIdx.x] + blocksum[threadIdx.x + 64];
    #pragma unroll
    for (int off = 32; off > 0; off >>= 1)
        v += __shfl_down(v, off, 64);
    if (threadIdx.x == 0) out[0] = v;
}

extern "C" void kernel_launch(void* const* d_in, const int* in_sizes, int n_in,
                              void* d_out, int out_size, void* d_ws, size_t ws_size,
                              hipStream_t stream) {
    const float* y_true = (const float*)d_in[0];
    const float* y_pred = (const float*)d_in[1];
    float* out = (float*)d_out;

    float* part     = (float*)d_ws;                 // RC*CDN floats = 8 MiB
    float* blocksum = part + (size_t)RC * CDN;      // RBLK floats

    chamfer_kernel<<<dim3(RC, DIRS, BB), TPB, 0, stream>>>(y_true, y_pred, part);
    reduce_kernel<<<RBLK, TPB, 0, stream>>>(y_true, y_pred, part, blocksum);
    final_kernel<<<1, 64, 0, stream>>>(blocksum, out);
}